// Round 1
// 369.844 us; speedup vs baseline: 1.0424x; 1.0424x over previous
//
#include <hip/hip_runtime.h>
#include <math.h>

// ---------------------------------------------------------------------------
// DynamicGNN: GCN -> SAGE(mean) -> GAT(1 head) -> GCN(128->64)
// N=50000, E=1.6M, D=128, OUT=64.
// v13: gather rework — uint4 (16B/lane) gathers (LPN 32->16 / 16->8),
//      per-block LDS-staged CSR src slice (1 coalesced read per edge),
//      GAT edge weights computed once per edge into LDS with factored 1/den.
//      CSR build + MFMA GEMMs unchanged. 12 dispatches total.
// ---------------------------------------------------------------------------

#define BUCKET_BITS 8
#define BUCKET_SZ   256
#define NBMAX       256
#define CAP         10240   // padded bucket capacity (~8163 +- 90 expected)
#define CAPE        2048    // staged edges per gather block (>=30 sigma headroom)

typedef short short8 __attribute__((ext_vector_type(8)));
typedef float f32x4 __attribute__((ext_vector_type(4)));
typedef unsigned int u32x4 __attribute__((ext_vector_type(4)));
typedef unsigned short u16x8 __attribute__((ext_vector_type(8)));

__device__ __forceinline__ float leaky02(float x) { return x > 0.0f ? x : 0.2f * x; }
__device__ __forceinline__ float bflo(unsigned u) { return __uint_as_float(u << 16); }
__device__ __forceinline__ float bfhi(unsigned u) { return __uint_as_float(u & 0xFFFF0000u); }
__device__ __forceinline__ unsigned short f2bf(float f) {
    unsigned u = __float_as_uint(f);
    u += 0x7FFFu + ((u >> 16) & 1u);   // round-to-nearest-even
    return (unsigned short)(u >> 16);
}

// ---------------- MFMA GEMM: C16 = bf16( scale? * (A@W (+A1@W1)) + bias )
// 256 thr = 4 waves; block = 64 rows; wave = 16 rows x NO cols.
// mfma_f32_16x16x32_bf16: A lane(m=lane&15,q=lane>>4) k=q*8+j; B lane(n,q);
// D col=lane&15, row=q*4+reg.  DOTS: as_/ad_ row dots via 16-lane reduce.
template<int NO, bool AFP32, bool SCALE, bool BIASRELU, bool DUAL, bool DOTS>
__global__ __launch_bounds__(256) void mgemm_k(
    const void* __restrict__ Av, const float* __restrict__ W,
    const void* __restrict__ A1v, const float* __restrict__ W1,
    unsigned short* __restrict__ C16,
    const float* __restrict__ scale, const float* __restrict__ bias,
    const float* __restrict__ a_s, const float* __restrict__ a_d,
    float* __restrict__ as_, float* __restrict__ ad_, int n)
{
    constexpr int CT = NO / 16;
    __shared__ unsigned short Wp[128 * NO];   // packed B-frags (32/16 KB)
    const int tid = threadIdx.x;
    const int wave = tid >> 6, lane = tid & 63;
    const int q = lane >> 4, ml = lane & 15;
    const int row0 = blockIdx.x * 64 + wave * 16;
    int arow = row0 + ml; if (arow >= n) arow = n - 1;

    f32x4 acc[CT];
#pragma unroll
    for (int c = 0; c < CT; c++) acc[c] = {0.f, 0.f, 0.f, 0.f};

    for (int half = 0; half < (DUAL ? 2 : 1); half++) {
        const float* Wsrc = half ? W1 : W;
        const void* Asrc = half ? A1v : Av;
        __syncthreads();
        for (int f = tid; f < 64 * (NO / 4); f += 256) {
            const int kp = f / (NO / 4);
            const int n4 = f % (NO / 4);
            const float4 a = *(const float4*)(Wsrc + (size_t)(2 * kp) * NO + n4 * 4);
            const float4 b = *(const float4*)(Wsrc + (size_t)(2 * kp + 1) * NO + n4 * 4);
            const int k = 2 * kp, kb = k >> 5, qq = (k >> 3) & 3, p = (k & 7) >> 1;
            const float av[4] = {a.x, a.y, a.z, a.w};
            const float bv[4] = {b.x, b.y, b.z, b.w};
#pragma unroll
            for (int j = 0; j < 4; j++) {
                int col = n4 * 4 + j;
                int c = col >> 4, nl = col & 15;
                unsigned pk = (unsigned)f2bf(av[j]) | ((unsigned)f2bf(bv[j]) << 16);
                ((unsigned*)Wp)[(((kb * CT + c) * 64) + qq * 16 + nl) * 4 + p] = pk;
            }
        }
        __syncthreads();
#pragma unroll
        for (int kb = 0; kb < 4; kb++) {
            short8 afr;
            if (AFP32) {
                const float* Af = (const float*)Asrc + (size_t)arow * 128 + kb * 32 + q * 8;
#pragma unroll
                for (int j = 0; j < 8; j++) afr[j] = (short)f2bf(Af[j]);
            } else {
                afr = *(const short8*)((const unsigned short*)Asrc +
                                       (size_t)arow * 128 + kb * 32 + q * 8);
            }
#pragma unroll
            for (int c = 0; c < CT; c++) {
                short8 bfr = *(const short8*)(Wp + ((size_t)(kb * CT + c) * 64 + lane) * 8);
                acc[c] = __builtin_amdgcn_mfma_f32_16x16x32_bf16(afr, bfr, acc[c], 0, 0, 0);
            }
        }
    }

    if (DOTS) {
        float ps[4] = {0.f, 0.f, 0.f, 0.f}, pd[4] = {0.f, 0.f, 0.f, 0.f};
#pragma unroll
        for (int c = 0; c < CT; c++) {
            float sv = a_s[c * 16 + ml], dv = a_d[c * 16 + ml];
#pragma unroll
            for (int r = 0; r < 4; r++) {
                ps[r] = fmaf(acc[c][r], sv, ps[r]);
                pd[r] = fmaf(acc[c][r], dv, pd[r]);
            }
        }
#pragma unroll
        for (int off = 1; off < 16; off <<= 1) {
#pragma unroll
            for (int r = 0; r < 4; r++) {
                ps[r] += __shfl_xor(ps[r], off, 64);
                pd[r] += __shfl_xor(pd[r], off, 64);
            }
        }
        if (ml == 0) {
#pragma unroll
            for (int r = 0; r < 4; r++) {
                int row = row0 + q * 4 + r;
                if (row < n) { as_[row] = ps[r]; ad_[row] = pd[r]; }
            }
        }
    }

    float sc[4];
    if (SCALE) {
#pragma unroll
        for (int r = 0; r < 4; r++) {
            int row = row0 + q * 4 + r;
            sc[r] = scale[row < n ? row : 0];
        }
    }
#pragma unroll
    for (int c = 0; c < CT; c++) {
        float bv = BIASRELU ? bias[c * 16 + ml] : 0.0f;
#pragma unroll
        for (int r = 0; r < 4; r++) {
            int row = row0 + q * 4 + r;
            if (row < n) {
                float v = acc[c][r];
                if (SCALE) v *= sc[r];
                if (BIASRELU) v = fmaxf(v + bv, 0.0f);
                C16[(size_t)row * NO + c * 16 + ml] = f2bf(v);
            }
        }
    }
}

// ---------------- CSR build: padded buckets (no pre-histogram) ----------------
__global__ void binit_k(int* __restrict__ bcur, int nb) {
    int t = threadIdx.x;
    if (t < nb) bcur[t] = t * CAP;
}

#define PART_CH 4096
__global__ __launch_bounds__(256) void part_k(
    const int* __restrict__ src, const int* __restrict__ dst,
    int* __restrict__ bcur, unsigned long long* __restrict__ part, int nE)
{
    __shared__ int cnt[NBMAX];
    __shared__ int cur[NBMAX];
    const int base = blockIdx.x * PART_CH;
    const int t = threadIdx.x;
    cnt[t] = 0;
    __syncthreads();
    int d[PART_CH / 256], s[PART_CH / 256];
#pragma unroll
    for (int j = 0; j < PART_CH / 256; j++) {
        int e = base + j * 256 + t;
        if (e < nE) {
            d[j] = dst[e]; s[j] = src[e];
            atomicAdd(&cnt[d[j] >> BUCKET_BITS], 1);
        } else d[j] = -1;
    }
    __syncthreads();
    {
        int c = cnt[t];
        cur[t] = c ? atomicAdd(&bcur[t], c) : 0;
    }
    __syncthreads();
#pragma unroll
    for (int j = 0; j < PART_CH / 256; j++) {
        if (d[j] >= 0) {
            int p = atomicAdd(&cur[d[j] >> BUCKET_BITS], 1);
            part[p] = ((unsigned long long)(unsigned)d[j] << 32) | (unsigned)s[j];
        }
    }
}

// scan bucket counts (bcur[b]-b*CAP) -> bofs (CSR bucket bases)
__global__ __launch_bounds__(256) void bscan_k(const int* __restrict__ bcur,
                                               int* __restrict__ bofs, int nb) {
    __shared__ int sm[256];
    const int t = threadIdx.x;
    int v = (t < nb) ? (bcur[t] - t * CAP) : 0;
    sm[t] = v;
    __syncthreads();
    for (int off = 1; off < 256; off <<= 1) {
        int tv = (t >= off) ? sm[t - off] : 0;
        __syncthreads();
        sm[t] += tv;
        __syncthreads();
    }
    if (t < nb) {
        bofs[t] = sm[t] - v;
        if (t == nb - 1) bofs[nb] = sm[t];
    }
}

__global__ __launch_bounds__(256) void csr_k(
    const unsigned long long* __restrict__ part, const int* __restrict__ bcur,
    const int* __restrict__ bofs, int* __restrict__ rowptr, int* __restrict__ srcs,
    float* __restrict__ dinv, float* __restrict__ invm, int n, int nE)
{
    __shared__ int lcnt[BUCKET_SZ];
    __shared__ int sm[BUCKET_SZ];
    __shared__ int lcur[BUCKET_SZ];
    const int b = blockIdx.x;
    const int t = threadIdx.x;
    const int base_in = b * CAP;
    const int cntE = bcur[b] - base_in;
    const int base_out = bofs[b];

    lcnt[t] = 0;
    __syncthreads();
#pragma unroll 4
    for (int e = t; e < cntE; e += 256) {
        int dl = (int)(part[base_in + e] >> 32) & (BUCKET_SZ - 1);
        atomicAdd(&lcnt[dl], 1);
    }
    __syncthreads();
    int v = lcnt[t];
    sm[t] = v;
    __syncthreads();
    for (int off = 1; off < 256; off <<= 1) {
        int tv = (t >= off) ? sm[t - off] : 0;
        __syncthreads();
        sm[t] += tv;
        __syncthreads();
    }
    const int excl = sm[t] - v;
    const int node = (b << BUCKET_BITS) + t;
    if (node < n) {
        rowptr[node] = base_out + excl;
        float dg = (float)v;
        dinv[node] = rsqrtf(dg + 1.0f);
        invm[node] = 1.0f / fmaxf(dg, 1.0f);
        if (node == n - 1) rowptr[n] = nE;
    }
    lcur[t] = excl;
    __syncthreads();
#pragma unroll 4
    for (int e = t; e < cntE; e += 256) {
        unsigned long long w = part[base_in + e];
        int dl = (int)(w >> 32) & (BUCKET_SZ - 1);
        int pos = atomicAdd(&lcur[dl], 1);
        srcs[base_out + pos] = (int)(unsigned)w;
    }
}

// ---------------- bf16 gather v13: uint4/lane, LDS-staged srcs + GAT weights
// MODE 0: SAGE mean = invm * sum(H[s]); emit bf16.
// MODE 1: GCN: dinv_d * (sum + self) + bias, relu; emit bf16 (H pre-scaled).
// MODE 2: GAT: per-edge exp->LDS (once), out = rden*sum(w*h) + sw*self + b, relu.
// MODE 3: GCN out: dinv_d * (sum + self) + bias; fp32 out.
template<int LPN, int MODE, bool OV>
__device__ __forceinline__ void gath_loop(
    const u32x4* __restrict__ H4, const int* __restrict__ srcs,
    const int* lsrc, const float* lw, const float* __restrict__ as_,
    float ad_d, int beg, int end, int beg_blk, int lane, float* acc)
{
    const u32x4* __restrict__ Hl = H4 + lane;
    int k = beg;
    for (; k + 8 <= end; k += 8) {
        unsigned sidx[8]; float wv[8];
#pragma unroll
        for (int j = 0; j < 8; j++) {
            int ofs = k + j - beg_blk;
            if (OV) {
                int ofc = ofs < CAPE ? ofs : CAPE - 1;
                int s = (ofs < CAPE) ? lsrc[ofc] : srcs[k + j];
                sidx[j] = (unsigned)s;
                if (MODE == 2)
                    wv[j] = (ofs < CAPE) ? lw[ofc] : __expf(leaky02(as_[s] + ad_d));
            } else {
                sidx[j] = (unsigned)lsrc[ofs];
                if (MODE == 2) wv[j] = lw[ofs];
            }
        }
        u32x4 h[8];
#pragma unroll
        for (int j = 0; j < 8; j++) h[j] = Hl[(size_t)sidx[j] * LPN];
#pragma unroll
        for (int j = 0; j < 8; j++) {
#pragma unroll
            for (int c = 0; c < 4; c++) {
                if (MODE == 2) {
                    acc[2 * c]     = fmaf(wv[j], bflo(h[j][c]), acc[2 * c]);
                    acc[2 * c + 1] = fmaf(wv[j], bfhi(h[j][c]), acc[2 * c + 1]);
                } else {
                    acc[2 * c]     += bflo(h[j][c]);
                    acc[2 * c + 1] += bfhi(h[j][c]);
                }
            }
        }
    }
    if (k < end) {
        unsigned sidx[8]; float wv[8];
#pragma unroll
        for (int j = 0; j < 8; j++) {
            int kk = k + j;
            bool act = kk < end;
            int kc = act ? kk : end - 1;
            int ofs = kc - beg_blk;
            int s; float w0 = 1.0f;
            if (OV) {
                int ofc = ofs < CAPE ? ofs : CAPE - 1;
                s = (ofs < CAPE) ? lsrc[ofc] : srcs[kc];
                if (MODE == 2)
                    w0 = (ofs < CAPE) ? lw[ofc] : __expf(leaky02(as_[s] + ad_d));
            } else {
                s = lsrc[ofs];
                if (MODE == 2) w0 = lw[ofs];
            }
            sidx[j] = (unsigned)s;
            wv[j] = act ? w0 : 0.0f;
        }
        u32x4 h[8];
#pragma unroll
        for (int j = 0; j < 8; j++) h[j] = Hl[(size_t)sidx[j] * LPN];
#pragma unroll
        for (int j = 0; j < 8; j++) {
#pragma unroll
            for (int c = 0; c < 4; c++) {
                acc[2 * c]     = fmaf(wv[j], bflo(h[j][c]), acc[2 * c]);
                acc[2 * c + 1] = fmaf(wv[j], bfhi(h[j][c]), acc[2 * c + 1]);
            }
        }
    }
}

template<int F, int MODE>
__global__ __launch_bounds__(256) void gatherbf_k(
    const unsigned short* __restrict__ H16, float* __restrict__ outf,
    unsigned short* __restrict__ out16,
    const int* __restrict__ rowptr, const int* __restrict__ srcs,
    const float* __restrict__ dinv, const float* __restrict__ as_,
    const float* __restrict__ ad_, const float* __restrict__ bias, int n)
{
    constexpr int LPN = F / 8;        // lanes per node, uint4 = 8 bf16 ch/lane
    constexpr int NPB = 256 / LPN;    // nodes per block
    __shared__ int lsrc[CAPE];
    __shared__ float lw[(MODE == 2) ? CAPE : 1];

    const int tid = (int)threadIdx.x;
    const int node0 = (int)blockIdx.x * NPB;
    const int nodeN = min(node0 + NPB, n);
    const int beg_blk = rowptr[node0];
    const int end_blk = rowptr[nodeN];
    const int cnt = end_blk - beg_blk;
    const int cl = min(cnt, CAPE);
    for (int i = tid; i < cl; i += 256) lsrc[i] = srcs[beg_blk + i];
    __syncthreads();

    const int node = node0 + tid / LPN;
    const int lane = tid & (LPN - 1);
    const bool alive = node < n;
    int beg = 0, end = 0;
    if (alive) { beg = rowptr[node]; end = rowptr[node + 1]; }

    float ad_d = 0.f, rden = 0.f, sw = 0.f;
    if (MODE == 2) {
        if (alive) {
            ad_d = ad_[node];
            float self_e = __expf(leaky02(as_[node] + ad_d));
            float psum = 0.f;
            for (int kk = beg + lane; kk < end; kk += LPN) {
                int ofs = kk - beg_blk;
                int s = (ofs < CAPE) ? lsrc[ofs < CAPE ? ofs : 0] : srcs[kk];
                float wv = __expf(leaky02(as_[s] + ad_d));
                if (ofs < CAPE) lw[ofs] = wv;
                psum += wv;
            }
#pragma unroll
            for (int off = LPN / 2; off > 0; off >>= 1)
                psum += __shfl_xor(psum, off, 64);
            rden = 1.0f / (psum + self_e);
            sw = self_e * rden;     // self alpha
        }
        __syncthreads();
    }

    float acc[8];
#pragma unroll
    for (int j = 0; j < 8; j++) acc[j] = 0.f;

    const u32x4* __restrict__ H4 = (const u32x4*)H16;
    if (alive) {
        if (cnt <= CAPE)
            gath_loop<LPN, MODE, false>(H4, srcs, lsrc, lw, as_, ad_d,
                                        beg, end, beg_blk, lane, acc);
        else
            gath_loop<LPN, MODE, true>(H4, srcs, lsrc, lw, as_, ad_d,
                                       beg, end, beg_blk, lane, acc);
    }
    if (!alive) return;   // all barriers already passed

    const size_t orow = (size_t)node * LPN + lane;
    float r[8];
    if (MODE == 0) {
        float sc = dinv[node];   // invm via dinv arg
#pragma unroll
        for (int j = 0; j < 8; j++) r[j] = acc[j] * sc;
    } else {
        u32x4 su = H4[orow];
        float sv[8];
#pragma unroll
        for (int c = 0; c < 4; c++) { sv[2 * c] = bflo(su[c]); sv[2 * c + 1] = bfhi(su[c]); }
        const float4* b4 = (const float4*)bias;
        float4 ba = b4[lane * 2], bb = b4[lane * 2 + 1];
        float bv[8] = {ba.x, ba.y, ba.z, ba.w, bb.x, bb.y, bb.z, bb.w};
        if (MODE == 2) {
#pragma unroll
            for (int j = 0; j < 8; j++)
                r[j] = fmaxf(fmaf(rden, acc[j], fmaf(sw, sv[j], bv[j])), 0.f);
        } else {
            float dv = dinv[node];
#pragma unroll
            for (int j = 0; j < 8; j++) {
                r[j] = dv * (acc[j] + sv[j]) + bv[j];
                if (MODE == 1) r[j] = fmaxf(r[j], 0.f);
            }
        }
    }
    if (MODE == 3) {
        float4 ra = {r[0], r[1], r[2], r[3]}, rb = {r[4], r[5], r[6], r[7]};
        ((float4*)outf)[orow * 2]     = ra;
        ((float4*)outf)[orow * 2 + 1] = rb;
    } else {
        u16x8 qv;
#pragma unroll
        for (int j = 0; j < 8; j++) qv[j] = f2bf(r[j]);
        ((u16x8*)out16)[orow] = qv;
    }
}

// ---------------------------------------------------------------------------
extern "C" void kernel_launch(void* const* d_in, const int* in_sizes, int n_in,
                              void* d_out, int out_size, void* d_ws, size_t ws_size,
                              hipStream_t stream)
{
    const float* x   = (const float*)d_in[0];
    const int*   ei  = (const int*)d_in[1];
    const float* W1  = (const float*)d_in[2];
    const float* b1  = (const float*)d_in[3];
    const float* Wl  = (const float*)d_in[4];
    const float* Wr  = (const float*)d_in[5];
    const float* bs  = (const float*)d_in[6];
    const float* Wg  = (const float*)d_in[7];
    const float* a_s = (const float*)d_in[8];
    const float* a_d = (const float*)d_in[9];
    const float* bg  = (const float*)d_in[10];
    const float* Wo  = (const float*)d_in[11];
    const float* bo  = (const float*)d_in[12];

    const int n  = in_sizes[0] / 128;
    const int nE = in_sizes[1] / 2;
    const int* src = ei;
    const int* dst = ei + nE;

    char* w = (char*)d_ws;
    auto alloc = [&](size_t bytes) { char* p = w; w += (bytes + 255) & ~(size_t)255; return p; };
    unsigned short* S0 = (unsigned short*)alloc((size_t)n * 128 * 2);
    unsigned short* S1 = (unsigned short*)alloc((size_t)n * 128 * 2);
    unsigned short* S2 = (unsigned short*)alloc((size_t)n * 128 * 2);
    const int nbv = (n + BUCKET_SZ - 1) / BUCKET_SZ;
    unsigned long long* part = (unsigned long long*)alloc((size_t)nbv * CAP * 8);
    int*   srcs   = (int*)alloc((size_t)nE * 4);
    int*   rowptr = (int*)alloc((size_t)(n + 1) * 4);
    int*   bofs   = (int*)alloc((NBMAX + 1) * 4);
    int*   bcur   = (int*)alloc(NBMAX * 4);
    float* dinv   = (float*)alloc((size_t)n * 4);
    float* invm   = (float*)alloc((size_t)n * 4);
    float* as_    = (float*)alloc((size_t)n * 4);
    float* ad_    = (float*)alloc((size_t)n * 4);

    const int TB = 256;
    auto cdiv = [](long long a, long long b) { return (int)((a + b - 1) / b); };
    const int nb     = nbv;
    const int gPart  = cdiv(nE, PART_CH);
    const int gGemm  = cdiv(n, 64);
    const int gGa128 = cdiv(n, 16);   // NPB=16 for F=128 (LPN=16)
    const int gGa64  = cdiv(n, 32);   // NPB=32 for F=64  (LPN=8)

    // ---- CSR build: padded-bucket partition -> scan -> per-bucket LDS CSR
    binit_k<<<1, 256, 0, stream>>>(bcur, nb);
    part_k<<<gPart, TB, 0, stream>>>(src, dst, bcur, part, nE);
    bscan_k<<<1, 256, 0, stream>>>(bcur, bofs, nb);
    csr_k<<<nb, TB, 0, stream>>>(part, bcur, bofs, rowptr, srcs, dinv, invm, n, nE);

    // ---- Layer 1: GCN — x@W1 scaled by dinv[row] -> S0; gather -> S1 (=h1)
    mgemm_k<128, true, true, false, false, false><<<gGemm, TB, 0, stream>>>(
        x, W1, nullptr, nullptr, S0, dinv, nullptr, nullptr, nullptr, nullptr, nullptr, n);
    gatherbf_k<128, 1><<<gGa128, TB, 0, stream>>>(S0, nullptr, S1, rowptr, srcs,
                                                  dinv, nullptr, nullptr, b1, n);

    // ---- Layer 2: SAGE — mean(S1) -> S0; dual GEMM mean@Wl + h1@Wr -> S2 (=h2)
    gatherbf_k<128, 0><<<gGa128, TB, 0, stream>>>(S1, nullptr, S0, rowptr, srcs,
                                                  invm, nullptr, nullptr, nullptr, n);
    mgemm_k<128, false, false, true, true, false><<<gGemm, TB, 0, stream>>>(
        S0, Wl, S1, Wr, S2, nullptr, bs, nullptr, nullptr, nullptr, nullptr, n);

    // ---- Layer 3: GAT — h2@Wg -> S1 (+fused dots); fused-softmax gather -> S0
    mgemm_k<128, false, false, false, false, true><<<gGemm, TB, 0, stream>>>(
        S2, Wg, nullptr, nullptr, S1, nullptr, nullptr, a_s, a_d, as_, ad_, n);
    gatherbf_k<128, 2><<<gGa128, TB, 0, stream>>>(S1, nullptr, S0, rowptr, srcs,
                                                  nullptr, as_, ad_, bg, n);

    // ---- Output: h3@Wo scaled by dinv[row] -> S2; gather -> d_out (fp32)
    mgemm_k<64, false, true, false, false, false><<<gGemm, TB, 0, stream>>>(
        S0, Wo, nullptr, nullptr, S2, dinv, nullptr, nullptr, nullptr, nullptr, nullptr, n);
    gatherbf_k<64, 3><<<gGa64, TB, 0, stream>>>(S2, (float*)d_out, nullptr, rowptr, srcs,
                                                dinv, nullptr, nullptr, bo, n);
}

// Round 2
// 357.585 us; speedup vs baseline: 1.0781x; 1.0343x over previous
//
#include <hip/hip_runtime.h>
#include <math.h>

// ---------------------------------------------------------------------------
// DynamicGNN: GCN -> SAGE(mean) -> GAT(1 head) -> GCN(128->64)
// N=50000, E=1.6M, D=128, OUT=64.
// v14: L2-resident gather. All bf16 H tensors channel-blocked [cb][N][32ch];
//      gather blocks handle one 32-ch slice (3.2MB < 4MB L2/XCD) with the
//      slice pinned to XCDs via blockIdx%8 (cb=(bid&7)/XPC). GAT softmax
//      hoisted to gatw_k (per-edge exp weights + per-node rden/self-alpha
//      precomputed once). GEMM A-reads/C-writes re-indexed for blocked layout.
//      13 dispatches total.
// ---------------------------------------------------------------------------

#define BUCKET_BITS 8
#define BUCKET_SZ   256
#define NBMAX       256
#define CAP         10240   // padded bucket capacity (~8163 +- 90 expected)
#define CAPE        2560    // staged edges per gather block (mean 2048 + 11 sigma)

typedef short short8 __attribute__((ext_vector_type(8)));
typedef float f32x4 __attribute__((ext_vector_type(4)));
typedef unsigned int u32x4 __attribute__((ext_vector_type(4)));
typedef unsigned short u16x8 __attribute__((ext_vector_type(8)));

__device__ __forceinline__ float leaky02(float x) { return x > 0.0f ? x : 0.2f * x; }
__device__ __forceinline__ float bflo(unsigned u) { return __uint_as_float(u << 16); }
__device__ __forceinline__ float bfhi(unsigned u) { return __uint_as_float(u & 0xFFFF0000u); }
__device__ __forceinline__ unsigned short f2bf(float f) {
    unsigned u = __float_as_uint(f);
    u += 0x7FFFu + ((u >> 16) & 1u);   // round-to-nearest-even
    return (unsigned short)(u >> 16);
}

// ---------------- MFMA GEMM: C16 = bf16( scale? * (A@W (+A1@W1)) + bias )
// 256 thr = 4 waves; block = 64 rows; wave = 16 rows x NO cols.
// bf16 A tensors are channel-blocked [kb][n][32]; fp32 A (layer 1) is row-major.
// C16 written channel-blocked [col>>5][n][32].
template<int NO, bool AFP32, bool SCALE, bool BIASRELU, bool DUAL, bool DOTS>
__global__ __launch_bounds__(256) void mgemm_k(
    const void* __restrict__ Av, const float* __restrict__ W,
    const void* __restrict__ A1v, const float* __restrict__ W1,
    unsigned short* __restrict__ C16,
    const float* __restrict__ scale, const float* __restrict__ bias,
    const float* __restrict__ a_s, const float* __restrict__ a_d,
    float* __restrict__ as_, float* __restrict__ ad_, int n)
{
    constexpr int CT = NO / 16;
    __shared__ unsigned short Wp[128 * NO];   // packed B-frags (32/16 KB)
    const int tid = threadIdx.x;
    const int wave = tid >> 6, lane = tid & 63;
    const int q = lane >> 4, ml = lane & 15;
    const int row0 = blockIdx.x * 64 + wave * 16;
    int arow = row0 + ml; if (arow >= n) arow = n - 1;

    f32x4 acc[CT];
#pragma unroll
    for (int c = 0; c < CT; c++) acc[c] = {0.f, 0.f, 0.f, 0.f};

    for (int half = 0; half < (DUAL ? 2 : 1); half++) {
        const float* Wsrc = half ? W1 : W;
        const void* Asrc = half ? A1v : Av;
        __syncthreads();
        for (int f = tid; f < 64 * (NO / 4); f += 256) {
            const int kp = f / (NO / 4);
            const int n4 = f % (NO / 4);
            const float4 a = *(const float4*)(Wsrc + (size_t)(2 * kp) * NO + n4 * 4);
            const float4 b = *(const float4*)(Wsrc + (size_t)(2 * kp + 1) * NO + n4 * 4);
            const int k = 2 * kp, kb = k >> 5, qq = (k >> 3) & 3, p = (k & 7) >> 1;
            const float av[4] = {a.x, a.y, a.z, a.w};
            const float bv[4] = {b.x, b.y, b.z, b.w};
#pragma unroll
            for (int j = 0; j < 4; j++) {
                int col = n4 * 4 + j;
                int c = col >> 4, nl = col & 15;
                unsigned pk = (unsigned)f2bf(av[j]) | ((unsigned)f2bf(bv[j]) << 16);
                ((unsigned*)Wp)[(((kb * CT + c) * 64) + qq * 16 + nl) * 4 + p] = pk;
            }
        }
        __syncthreads();
#pragma unroll
        for (int kb = 0; kb < 4; kb++) {
            short8 afr;
            if (AFP32) {
                const float* Af = (const float*)Asrc + (size_t)arow * 128 + kb * 32 + q * 8;
#pragma unroll
                for (int j = 0; j < 8; j++) afr[j] = (short)f2bf(Af[j]);
            } else {
                // channel-blocked bf16: slice kb, row arow, ch q*8..q*8+7
                afr = *(const short8*)((const unsigned short*)Asrc +
                                       ((size_t)kb * n + arow) * 32 + q * 8);
            }
#pragma unroll
            for (int c = 0; c < CT; c++) {
                short8 bfr = *(const short8*)(Wp + ((size_t)(kb * CT + c) * 64 + lane) * 8);
                acc[c] = __builtin_amdgcn_mfma_f32_16x16x32_bf16(afr, bfr, acc[c], 0, 0, 0);
            }
        }
    }

    if (DOTS) {
        float ps[4] = {0.f, 0.f, 0.f, 0.f}, pd[4] = {0.f, 0.f, 0.f, 0.f};
#pragma unroll
        for (int c = 0; c < CT; c++) {
            float sv = a_s[c * 16 + ml], dv = a_d[c * 16 + ml];
#pragma unroll
            for (int r = 0; r < 4; r++) {
                ps[r] = fmaf(acc[c][r], sv, ps[r]);
                pd[r] = fmaf(acc[c][r], dv, pd[r]);
            }
        }
#pragma unroll
        for (int off = 1; off < 16; off <<= 1) {
#pragma unroll
            for (int r = 0; r < 4; r++) {
                ps[r] += __shfl_xor(ps[r], off, 64);
                pd[r] += __shfl_xor(pd[r], off, 64);
            }
        }
        if (ml == 0) {
#pragma unroll
            for (int r = 0; r < 4; r++) {
                int row = row0 + q * 4 + r;
                if (row < n) { as_[row] = ps[r]; ad_[row] = pd[r]; }
            }
        }
    }

    float sc[4];
    if (SCALE) {
#pragma unroll
        for (int r = 0; r < 4; r++) {
            int row = row0 + q * 4 + r;
            sc[r] = scale[row < n ? row : 0];
        }
    }
#pragma unroll
    for (int c = 0; c < CT; c++) {
        float bv = BIASRELU ? bias[c * 16 + ml] : 0.0f;
        const int col = c * 16 + ml;
#pragma unroll
        for (int r = 0; r < 4; r++) {
            int row = row0 + q * 4 + r;
            if (row < n) {
                float v = acc[c][r];
                if (SCALE) v *= sc[r];
                if (BIASRELU) v = fmaxf(v + bv, 0.0f);
                C16[((size_t)(col >> 5) * n + row) * 32 + (col & 31)] = f2bf(v);
            }
        }
    }
}

// ---------------- CSR build: padded buckets (no pre-histogram) ----------------
__global__ void binit_k(int* __restrict__ bcur, int nb) {
    int t = threadIdx.x;
    if (t < nb) bcur[t] = t * CAP;
}

#define PART_CH 4096
__global__ __launch_bounds__(256) void part_k(
    const int* __restrict__ src, const int* __restrict__ dst,
    int* __restrict__ bcur, unsigned long long* __restrict__ part, int nE)
{
    __shared__ int cnt[NBMAX];
    __shared__ int cur[NBMAX];
    const int base = blockIdx.x * PART_CH;
    const int t = threadIdx.x;
    cnt[t] = 0;
    __syncthreads();
    int d[PART_CH / 256], s[PART_CH / 256];
#pragma unroll
    for (int j = 0; j < PART_CH / 256; j++) {
        int e = base + j * 256 + t;
        if (e < nE) {
            d[j] = dst[e]; s[j] = src[e];
            atomicAdd(&cnt[d[j] >> BUCKET_BITS], 1);
        } else d[j] = -1;
    }
    __syncthreads();
    {
        int c = cnt[t];
        cur[t] = c ? atomicAdd(&bcur[t], c) : 0;
    }
    __syncthreads();
#pragma unroll
    for (int j = 0; j < PART_CH / 256; j++) {
        if (d[j] >= 0) {
            int p = atomicAdd(&cur[d[j] >> BUCKET_BITS], 1);
            part[p] = ((unsigned long long)(unsigned)d[j] << 32) | (unsigned)s[j];
        }
    }
}

// scan bucket counts (bcur[b]-b*CAP) -> bofs (CSR bucket bases)
__global__ __launch_bounds__(256) void bscan_k(const int* __restrict__ bcur,
                                               int* __restrict__ bofs, int nb) {
    __shared__ int sm[256];
    const int t = threadIdx.x;
    int v = (t < nb) ? (bcur[t] - t * CAP) : 0;
    sm[t] = v;
    __syncthreads();
    for (int off = 1; off < 256; off <<= 1) {
        int tv = (t >= off) ? sm[t - off] : 0;
        __syncthreads();
        sm[t] += tv;
        __syncthreads();
    }
    if (t < nb) {
        bofs[t] = sm[t] - v;
        if (t == nb - 1) bofs[nb] = sm[t];
    }
}

__global__ __launch_bounds__(256) void csr_k(
    const unsigned long long* __restrict__ part, const int* __restrict__ bcur,
    const int* __restrict__ bofs, int* __restrict__ rowptr, int* __restrict__ srcs,
    float* __restrict__ dinv, float* __restrict__ invm, int n, int nE)
{
    __shared__ int lcnt[BUCKET_SZ];
    __shared__ int sm[BUCKET_SZ];
    __shared__ int lcur[BUCKET_SZ];
    const int b = blockIdx.x;
    const int t = threadIdx.x;
    const int base_in = b * CAP;
    const int cntE = bcur[b] - base_in;
    const int base_out = bofs[b];

    lcnt[t] = 0;
    __syncthreads();
#pragma unroll 4
    for (int e = t; e < cntE; e += 256) {
        int dl = (int)(part[base_in + e] >> 32) & (BUCKET_SZ - 1);
        atomicAdd(&lcnt[dl], 1);
    }
    __syncthreads();
    int v = lcnt[t];
    sm[t] = v;
    __syncthreads();
    for (int off = 1; off < 256; off <<= 1) {
        int tv = (t >= off) ? sm[t - off] : 0;
        __syncthreads();
        sm[t] += tv;
        __syncthreads();
    }
    const int excl = sm[t] - v;
    const int node = (b << BUCKET_BITS) + t;
    if (node < n) {
        rowptr[node] = base_out + excl;
        float dg = (float)v;
        dinv[node] = rsqrtf(dg + 1.0f);
        invm[node] = 1.0f / fmaxf(dg, 1.0f);
        if (node == n - 1) rowptr[n] = nE;
    }
    lcur[t] = excl;
    __syncthreads();
#pragma unroll 4
    for (int e = t; e < cntE; e += 256) {
        unsigned long long w = part[base_in + e];
        int dl = (int)(w >> 32) & (BUCKET_SZ - 1);
        int pos = atomicAdd(&lcur[dl], 1);
        srcs[base_out + pos] = (int)(unsigned)w;
    }
}

// ---------------- GAT edge-weight precompute: ew[e], rdn_[node], sw_[node] ----
__global__ __launch_bounds__(256) void gatw_k(
    const int* __restrict__ rowptr, const int* __restrict__ srcs,
    const float* __restrict__ as_, const float* __restrict__ ad_,
    float* __restrict__ ew, float* __restrict__ rdn_, float* __restrict__ sw_, int n)
{
    const int node = blockIdx.x * 32 + (threadIdx.x >> 3);
    const int lane = threadIdx.x & 7;
    if (node >= n) return;
    const int beg = rowptr[node], end = rowptr[node + 1];
    const float ad_d = ad_[node];
    float psum = 0.f;
    for (int k = beg + lane; k < end; k += 8) {
        float e = __expf(leaky02(as_[srcs[k]] + ad_d));
        ew[k] = e;
        psum += e;
    }
#pragma unroll
    for (int off = 4; off > 0; off >>= 1) psum += __shfl_xor(psum, off, 64);
    if (lane == 0) {
        float se = __expf(leaky02(as_[node] + ad_d));
        float r = 1.0f / (psum + se);
        rdn_[node] = r;
        sw_[node] = se * r;
    }
}

// ---------------- bf16 gather v14: 32-ch slices, XCD-pinned, LDS-staged edges
// H channel-blocked [NCB][n][32]. Block = (cb, node-group of 64); cb pinned to
// XCDs via blockIdx%8 so each XCD's L2 holds one 3.2MB slice.
// MODE 0: SAGE mean = invm * sum(H[s]); emit bf16 blocked.
// MODE 1: GCN: dinv_d * (sum + self) + bias, relu; emit bf16 blocked.
// MODE 2: GAT: rden * sum(ew*h) + sw*self + bias, relu (ew/rden/sw precomputed).
// MODE 3: GCN out: dinv_d * (sum + self) + bias; fp32 row-major out.
template<int MODE, bool OV>
__device__ __forceinline__ void gath_loop(
    const u32x4* __restrict__ Hc, const int* __restrict__ srcs,
    const float* __restrict__ ew, const int* lsrc, const float* lw,
    int beg, int end, int beg_blk, int lane, float* acc)
{
    int k = beg;
    for (; k + 8 <= end; k += 8) {
        unsigned sidx[8]; float wv[8];
#pragma unroll
        for (int j = 0; j < 8; j++) {
            int ofs = k + j - beg_blk;
            if (OV) {
                bool in = ofs < CAPE;
                int ofc = in ? ofs : 0;
                sidx[j] = (unsigned)(in ? lsrc[ofc] : srcs[k + j]);
                if (MODE == 2) wv[j] = in ? lw[ofc] : ew[k + j];
            } else {
                sidx[j] = (unsigned)lsrc[ofs];
                if (MODE == 2) wv[j] = lw[ofs];
            }
        }
        u32x4 h[8];
#pragma unroll
        for (int j = 0; j < 8; j++) h[j] = Hc[(size_t)sidx[j] * 4 + lane];
#pragma unroll
        for (int j = 0; j < 8; j++) {
#pragma unroll
            for (int c = 0; c < 4; c++) {
                if (MODE == 2) {
                    acc[2 * c]     = fmaf(wv[j], bflo(h[j][c]), acc[2 * c]);
                    acc[2 * c + 1] = fmaf(wv[j], bfhi(h[j][c]), acc[2 * c + 1]);
                } else {
                    acc[2 * c]     += bflo(h[j][c]);
                    acc[2 * c + 1] += bfhi(h[j][c]);
                }
            }
        }
    }
    if (k < end) {
        unsigned sidx[8]; float wv[8];
#pragma unroll
        for (int j = 0; j < 8; j++) {
            int kk = k + j;
            bool act = kk < end;
            int kc = act ? kk : end - 1;
            int ofs = kc - beg_blk;
            int s; float w0 = 1.0f;
            if (OV) {
                bool in = ofs < CAPE;
                int ofc = in ? ofs : 0;
                s = in ? lsrc[ofc] : srcs[kc];
                if (MODE == 2) w0 = in ? lw[ofc] : ew[kc];
            } else {
                s = lsrc[ofs];
                if (MODE == 2) w0 = lw[ofs];
            }
            sidx[j] = (unsigned)s;
            wv[j] = act ? w0 : 0.0f;
        }
        u32x4 h[8];
#pragma unroll
        for (int j = 0; j < 8; j++) h[j] = Hc[(size_t)sidx[j] * 4 + lane];
#pragma unroll
        for (int j = 0; j < 8; j++) {
#pragma unroll
            for (int c = 0; c < 4; c++) {
                acc[2 * c]     = fmaf(wv[j], bflo(h[j][c]), acc[2 * c]);
                acc[2 * c + 1] = fmaf(wv[j], bfhi(h[j][c]), acc[2 * c + 1]);
            }
        }
    }
}

template<int NCB, int MODE>
__global__ __launch_bounds__(256) void gatherbf_k(
    const unsigned short* __restrict__ H16, float* __restrict__ outf,
    unsigned short* __restrict__ out16,
    const int* __restrict__ rowptr, const int* __restrict__ srcs,
    const float* __restrict__ scl,   // MODE0: invm; MODE1/3: dinv; MODE2: rdn_
    const float* __restrict__ sw_,   // MODE2: self-alpha
    const float* __restrict__ ew,    // MODE2: per-edge exp weights
    const float* __restrict__ bias, int n)
{
    constexpr int XPC = 8 / NCB;     // XCDs per channel-slice
    constexpr int NPB = 64;          // nodes per block
    __shared__ int lsrc[CAPE];
    __shared__ float lw[(MODE == 2) ? CAPE : 1];

    const int bid = (int)blockIdx.x;
    const int xj = bid & 7;
    const int cb = xj / XPC;
    const int NG = (n + NPB - 1) / NPB;
    const int ng = (bid >> 3) * XPC + (xj % XPC);
    if (ng >= NG) return;

    const int tid = (int)threadIdx.x;
    const int node0 = ng * NPB;
    const int nodeN = min(node0 + NPB, n);
    const int beg_blk = rowptr[node0];
    const int end_blk = rowptr[nodeN];
    const int cnt = end_blk - beg_blk;
    const int cl = min(cnt, CAPE);
    for (int i = tid; i < cl; i += 256) {
        lsrc[i] = srcs[beg_blk + i];
        if (MODE == 2) lw[i] = ew[beg_blk + i];
    }
    __syncthreads();

    const int node = node0 + (tid >> 2);
    const int lane = tid & 3;
    if (node >= nodeN) return;
    const int beg = rowptr[node], end = rowptr[node + 1];
    const u32x4* __restrict__ Hc = (const u32x4*)H16 + (size_t)cb * n * 4;

    float acc[8];
#pragma unroll
    for (int j = 0; j < 8; j++) acc[j] = 0.f;

    if (cnt <= CAPE)
        gath_loop<MODE, false>(Hc, srcs, ew, lsrc, lw, beg, end, beg_blk, lane, acc);
    else
        gath_loop<MODE, true>(Hc, srcs, ew, lsrc, lw, beg, end, beg_blk, lane, acc);

    const size_t orow = ((size_t)cb * n + node) * 4 + lane;   // u16x8 units
    float r[8];
    if (MODE == 0) {
        float sc = scl[node];
#pragma unroll
        for (int j = 0; j < 8; j++) r[j] = acc[j] * sc;
    } else {
        u32x4 su = Hc[(size_t)node * 4 + lane];
        float sv[8];
#pragma unroll
        for (int c = 0; c < 4; c++) { sv[2 * c] = bflo(su[c]); sv[2 * c + 1] = bfhi(su[c]); }
        const float4* b4 = (const float4*)bias;
        float4 ba = b4[cb * 8 + lane * 2], bb = b4[cb * 8 + lane * 2 + 1];
        float bv[8] = {ba.x, ba.y, ba.z, ba.w, bb.x, bb.y, bb.z, bb.w};
        if (MODE == 2) {
            float rden = scl[node], sw = sw_[node];
#pragma unroll
            for (int j = 0; j < 8; j++)
                r[j] = fmaxf(fmaf(rden, acc[j], fmaf(sw, sv[j], bv[j])), 0.f);
        } else {
            float dv = scl[node];
#pragma unroll
            for (int j = 0; j < 8; j++) {
                r[j] = dv * (acc[j] + sv[j]) + bv[j];
                if (MODE == 1) r[j] = fmaxf(r[j], 0.f);
            }
        }
    }
    if (MODE == 3) {
        float4* o4 = (float4*)(outf + (size_t)node * 64 + cb * 32 + lane * 8);
        float4 ra = {r[0], r[1], r[2], r[3]}, rb = {r[4], r[5], r[6], r[7]};
        o4[0] = ra; o4[1] = rb;
    } else {
        u16x8 qv;
#pragma unroll
        for (int j = 0; j < 8; j++) qv[j] = f2bf(r[j]);
        ((u16x8*)out16)[orow] = qv;
    }
}

// ---------------------------------------------------------------------------
extern "C" void kernel_launch(void* const* d_in, const int* in_sizes, int n_in,
                              void* d_out, int out_size, void* d_ws, size_t ws_size,
                              hipStream_t stream)
{
    const float* x   = (const float*)d_in[0];
    const int*   ei  = (const int*)d_in[1];
    const float* W1  = (const float*)d_in[2];
    const float* b1  = (const float*)d_in[3];
    const float* Wl  = (const float*)d_in[4];
    const float* Wr  = (const float*)d_in[5];
    const float* bs  = (const float*)d_in[6];
    const float* Wg  = (const float*)d_in[7];
    const float* a_s = (const float*)d_in[8];
    const float* a_d = (const float*)d_in[9];
    const float* bg  = (const float*)d_in[10];
    const float* Wo  = (const float*)d_in[11];
    const float* bo  = (const float*)d_in[12];

    const int n  = in_sizes[0] / 128;
    const int nE = in_sizes[1] / 2;
    const int* src = ei;
    const int* dst = ei + nE;

    char* w = (char*)d_ws;
    auto alloc = [&](size_t bytes) { char* p = w; w += (bytes + 255) & ~(size_t)255; return p; };
    unsigned short* S0 = (unsigned short*)alloc((size_t)n * 128 * 2);
    unsigned short* S1 = (unsigned short*)alloc((size_t)n * 128 * 2);
    unsigned short* S2 = (unsigned short*)alloc((size_t)n * 128 * 2);
    const int nbv = (n + BUCKET_SZ - 1) / BUCKET_SZ;
    unsigned long long* part = (unsigned long long*)alloc((size_t)nbv * CAP * 8);
    int*   srcs   = (int*)alloc((size_t)nE * 4);
    int*   rowptr = (int*)alloc((size_t)(n + 1) * 4);
    int*   bofs   = (int*)alloc((NBMAX + 1) * 4);
    int*   bcur   = (int*)alloc(NBMAX * 4);
    float* dinv   = (float*)alloc((size_t)n * 4);
    float* invm   = (float*)alloc((size_t)n * 4);
    float* as_    = (float*)alloc((size_t)n * 4);
    float* ad_    = (float*)alloc((size_t)n * 4);
    float* ew     = (float*)alloc((size_t)nE * 4);
    float* rdn_   = (float*)alloc((size_t)n * 4);
    float* sw_    = (float*)alloc((size_t)n * 4);

    const int TB = 256;
    auto cdiv = [](long long a, long long b) { return (int)((a + b - 1) / b); };
    const int nb     = nbv;
    const int gPart  = cdiv(nE, PART_CH);
    const int gGemm  = cdiv(n, 64);
    const int NG     = cdiv(n, 64);            // node-groups of 64
    const int gGa128 = 8 * cdiv(NG, 2);        // NCB=4, 2 XCDs per slice
    const int gGa64  = 8 * cdiv(NG, 4);        // NCB=2, 4 XCDs per slice
    const int gGatw  = cdiv(n, 32);

    // ---- CSR build: padded-bucket partition -> scan -> per-bucket LDS CSR
    binit_k<<<1, 256, 0, stream>>>(bcur, nb);
    part_k<<<gPart, TB, 0, stream>>>(src, dst, bcur, part, nE);
    bscan_k<<<1, 256, 0, stream>>>(bcur, bofs, nb);
    csr_k<<<nb, TB, 0, stream>>>(part, bcur, bofs, rowptr, srcs, dinv, invm, n, nE);

    // ---- Layer 1: GCN — x@W1 scaled by dinv[row] -> S0; gather -> S1 (=h1)
    mgemm_k<128, true, true, false, false, false><<<gGemm, TB, 0, stream>>>(
        x, W1, nullptr, nullptr, S0, dinv, nullptr, nullptr, nullptr, nullptr, nullptr, n);
    gatherbf_k<4, 1><<<gGa128, TB, 0, stream>>>(S0, nullptr, S1, rowptr, srcs,
                                                dinv, nullptr, nullptr, b1, n);

    // ---- Layer 2: SAGE — mean(S1) -> S0; dual GEMM mean@Wl + h1@Wr -> S2 (=h2)
    gatherbf_k<4, 0><<<gGa128, TB, 0, stream>>>(S1, nullptr, S0, rowptr, srcs,
                                                invm, nullptr, nullptr, nullptr, n);
    mgemm_k<128, false, false, true, true, false><<<gGemm, TB, 0, stream>>>(
        S0, Wl, S1, Wr, S2, nullptr, bs, nullptr, nullptr, nullptr, nullptr, n);

    // ---- Layer 3: GAT — h2@Wg -> S1 (+fused dots); edge weights; gather -> S0
    mgemm_k<128, false, false, false, false, true><<<gGemm, TB, 0, stream>>>(
        S2, Wg, nullptr, nullptr, S1, nullptr, nullptr, a_s, a_d, as_, ad_, n);
    gatw_k<<<gGatw, TB, 0, stream>>>(rowptr, srcs, as_, ad_, ew, rdn_, sw_, n);
    gatherbf_k<4, 2><<<gGa128, TB, 0, stream>>>(S1, nullptr, S0, rowptr, srcs,
                                                rdn_, sw_, ew, bg, n);

    // ---- Output: h3@Wo scaled by dinv[row] -> S2; gather -> d_out (fp32)
    mgemm_k<64, false, true, false, false, false><<<gGemm, TB, 0, stream>>>(
        S0, Wo, nullptr, nullptr, S2, dinv, nullptr, nullptr, nullptr, nullptr, nullptr, n);
    gatherbf_k<2, 3><<<gGa64, TB, 0, stream>>>(S2, (float*)d_out, nullptr, rowptr, srcs,
                                               dinv, nullptr, nullptr, bo, n);
}